// Round 3
// baseline (2612.131 us; speedup 1.0000x reference)
//
#include <hip/hip_runtime.h>

// GCNII on MI355X, all fp32.
//   1. CSR build by dst (hist -> scan -> scatter), once per call
//   2. Wc[i] = theta_i*conv_w[i] + (1-theta_i)*I   (absorbs identity-mapping mix)
//   3. h0 = x@W_in + b_in
//   4. 8x fused layer: wave-per-row CSR gather (8-deep, float2/lane) -> support ->
//      LDS -> @Wc (global, L2-hot) -> relu -> store
//   5. out = h@W_out + b_out
// R2 change: wave-uniform row ownership (scalar csr path via readfirstlane),
// 8-deep gather unroll with masked tail, launch_bounds(256,8) for 100% occupancy.

constexpr int NN = 100000;
constexpr int EE = 3200000;

// ---------------- CSR build ----------------
__global__ void hist_kernel(const int* __restrict__ dst, int* __restrict__ cnt, int e) {
    int i = blockIdx.x * 256 + threadIdx.x;
    if (i < e) atomicAdd(&cnt[dst[i]], 1);
}

__global__ __launch_bounds__(1024) void scan_kernel(const int* __restrict__ cnt,
                                                    int* __restrict__ row_ptr,
                                                    int* __restrict__ cursor, int n) {
    __shared__ int wsum[16];
    __shared__ int s_carry;
    const int lane = threadIdx.x & 63, wid = threadIdx.x >> 6;
    if (threadIdx.x == 0) s_carry = 0;
    __syncthreads();
    for (int base = 0; base < n; base += 1024) {
        int i = base + threadIdx.x;
        int v = (i < n) ? cnt[i] : 0;
        int x = v;
        #pragma unroll
        for (int d = 1; d < 64; d <<= 1) {
            int y = __shfl_up(x, (unsigned)d);
            if (lane >= d) x += y;
        }
        if (lane == 63) wsum[wid] = x;
        __syncthreads();
        int woff = 0;
        for (int w = 0; w < wid; ++w) woff += wsum[w];
        int carry = s_carry;
        if (i < n) {
            int excl = carry + woff + x - v;
            row_ptr[i] = excl;
            cursor[i] = excl;
        }
        __syncthreads();
        if (threadIdx.x == 1023) s_carry = carry + woff + x;
        __syncthreads();
    }
    if (threadIdx.x == 0) row_ptr[n] = s_carry;
}

__global__ void scatter_kernel(const int* __restrict__ src, const int* __restrict__ dst,
                               const float* __restrict__ val, int* __restrict__ cursor,
                               int2* __restrict__ csr, int e) {
    int i = blockIdx.x * 256 + threadIdx.x;
    if (i < e) {
        int p = atomicAdd(&cursor[dst[i]], 1);
        csr[p] = make_int2(src[i], __float_as_int(val[i]));
    }
}

// ---------------- Wc = theta*W + (1-theta)*I ----------------
__global__ void prep_wc_kernel(const float* __restrict__ conv_w, float* __restrict__ Wc) {
    int layer = blockIdx.y;
    int idx = blockIdx.x * 256 + threadIdx.x;          // 0..16383
    float theta = logf(0.5f / (float)(layer + 1) + 1.0f);
    int k = idx >> 7, j = idx & 127;
    float w = conv_w[layer * 16384 + idx];
    Wc[layer * 16384 + idx] = theta * w + ((k == j) ? (1.0f - theta) : 0.0f);
}

// ---------------- fc_in: h0 = x@W_in + b_in ----------------
__global__ __launch_bounds__(256, 2) void fc_in_kernel(const float* __restrict__ x,
                                                       const float* __restrict__ W,
                                                       const float* __restrict__ b,
                                                       float* __restrict__ h0) {
    __shared__ float sW[128 * 128];   // 64KB
    __shared__ float sA[32 * 128];    // 16KB
    const int tid = threadIdx.x;
    #pragma unroll
    for (int t = 0; t < 16; ++t)
        ((float4*)sW)[t * 256 + tid] = ((const float4*)W)[t * 256 + tid];
    const float4* xs = (const float4*)(x + (size_t)blockIdx.x * 32 * 128);
    #pragma unroll
    for (int t = 0; t < 4; ++t)
        ((float4*)sA)[t * 256 + tid] = xs[t * 256 + tid];
    __syncthreads();

    const int rowg = tid >> 5, colg = tid & 31;
    float4 bias = ((const float4*)b)[colg];
    float acc[4][4];
    #pragma unroll
    for (int r = 0; r < 4; ++r) { acc[r][0] = bias.x; acc[r][1] = bias.y; acc[r][2] = bias.z; acc[r][3] = bias.w; }

    for (int k = 0; k < 128; ++k) {
        float4 w = *(const float4*)&sW[k * 128 + (colg << 2)];
        float s[4];
        #pragma unroll
        for (int r = 0; r < 4; ++r) s[r] = sA[((rowg << 2) + r) * 128 + k];
        #pragma unroll
        for (int r = 0; r < 4; ++r) {
            acc[r][0] = fmaf(s[r], w.x, acc[r][0]);
            acc[r][1] = fmaf(s[r], w.y, acc[r][1]);
            acc[r][2] = fmaf(s[r], w.z, acc[r][2]);
            acc[r][3] = fmaf(s[r], w.w, acc[r][3]);
        }
    }
    float* outp = h0 + (size_t)blockIdx.x * 32 * 128;
    #pragma unroll
    for (int r = 0; r < 4; ++r) {
        float4 o = make_float4(acc[r][0], acc[r][1], acc[r][2], acc[r][3]);
        *(float4*)(outp + ((rowg << 2) + r) * 128 + (colg << 2)) = o;
    }
}

// ---------------- fused layer ----------------
// Phase A: one wave per row (64 lanes x float2 = 512B). Row base is wave-uniform
//          (readfirstlane) -> csr/row_ptr on scalar path. 8 gathers in flight.
// Phase B: S (LDS, 16KB) @ Wc (global, L2-hot) -> relu -> store.
__global__ __launch_bounds__(256, 8) void layer_kernel(const float* __restrict__ h,
                                                       const float* __restrict__ h0,
                                                       const int2* __restrict__ csr,
                                                       const int* __restrict__ row_ptr,
                                                       const float* __restrict__ Wc,
                                                       float* __restrict__ hn) {
    __shared__ float sS[32 * 128];    // 16KB
    const int tid = threadIdx.x;
    const int wid = tid >> 6, lane = tid & 63;
    const int fo = lane << 1;               // float2 feature offset
    const int row0 = blockIdx.x * 32;
    const int rb = __builtin_amdgcn_readfirstlane(row0 + wid * 8);

    for (int rr = 0; rr < 8; ++rr) {
        const int r = rb + rr;
        const int e0 = row_ptr[r], e1 = row_ptr[r + 1];
        float2 acc0 = make_float2(0.f, 0.f), acc1 = make_float2(0.f, 0.f);
        int e = e0;
        for (; e + 8 <= e1; e += 8) {
            int2 p0 = csr[e + 0], p1 = csr[e + 1], p2 = csr[e + 2], p3 = csr[e + 3];
            int2 p4 = csr[e + 4], p5 = csr[e + 5], p6 = csr[e + 6], p7 = csr[e + 7];
            float2 g0 = *(const float2*)(h + ((size_t)p0.x << 7) + fo);
            float2 g1 = *(const float2*)(h + ((size_t)p1.x << 7) + fo);
            float2 g2 = *(const float2*)(h + ((size_t)p2.x << 7) + fo);
            float2 g3 = *(const float2*)(h + ((size_t)p3.x << 7) + fo);
            float2 g4 = *(const float2*)(h + ((size_t)p4.x << 7) + fo);
            float2 g5 = *(const float2*)(h + ((size_t)p5.x << 7) + fo);
            float2 g6 = *(const float2*)(h + ((size_t)p6.x << 7) + fo);
            float2 g7 = *(const float2*)(h + ((size_t)p7.x << 7) + fo);
            float v0 = __int_as_float(p0.y), v1 = __int_as_float(p1.y);
            float v2 = __int_as_float(p2.y), v3 = __int_as_float(p3.y);
            float v4 = __int_as_float(p4.y), v5 = __int_as_float(p5.y);
            float v6 = __int_as_float(p6.y), v7 = __int_as_float(p7.y);
            acc0.x = fmaf(v0, g0.x, acc0.x); acc0.y = fmaf(v0, g0.y, acc0.y);
            acc1.x = fmaf(v1, g1.x, acc1.x); acc1.y = fmaf(v1, g1.y, acc1.y);
            acc0.x = fmaf(v2, g2.x, acc0.x); acc0.y = fmaf(v2, g2.y, acc0.y);
            acc1.x = fmaf(v3, g3.x, acc1.x); acc1.y = fmaf(v3, g3.y, acc1.y);
            acc0.x = fmaf(v4, g4.x, acc0.x); acc0.y = fmaf(v4, g4.y, acc0.y);
            acc1.x = fmaf(v5, g5.x, acc1.x); acc1.y = fmaf(v5, g5.y, acc1.y);
            acc0.x = fmaf(v6, g6.x, acc0.x); acc0.y = fmaf(v6, g6.y, acc0.y);
            acc1.x = fmaf(v7, g7.x, acc1.x); acc1.y = fmaf(v7, g7.y, acc1.y);
        }
        if (e < e1) {                         // one masked 8-wide tail iteration
            int2 pk[8];
            #pragma unroll
            for (int k = 0; k < 8; ++k)
                pk[k] = csr[(e + k < e1) ? (e + k) : (e1 - 1)];
            #pragma unroll
            for (int k = 0; k < 8; ++k) {
                float v = (e + k < e1) ? __int_as_float(pk[k].y) : 0.f;
                float2 g = *(const float2*)(h + ((size_t)pk[k].x << 7) + fo);
                if (k & 1) { acc1.x = fmaf(v, g.x, acc1.x); acc1.y = fmaf(v, g.y, acc1.y); }
                else       { acc0.x = fmaf(v, g.x, acc0.x); acc0.y = fmaf(v, g.y, acc0.y); }
            }
        }
        float2 h0v = *(const float2*)(h0 + ((size_t)r << 7) + fo);
        float2 sv;
        sv.x = 0.9f * (acc0.x + acc1.x) + 0.1f * h0v.x;
        sv.y = 0.9f * (acc0.y + acc1.y) + 0.1f * h0v.y;
        *(float2*)&sS[(wid * 8 + rr) * 128 + fo] = sv;
    }
    __syncthreads();

    // Phase B: out = S @ Wc, relu, store. Wc read from global (64KB, L1/L2-hot).
    const int rowg = tid >> 5, colg = tid & 31;
    const float* wp = Wc + (colg << 2);
    float acc2[4][4] = {};
    for (int k = 0; k < 128; k += 2) {
        float4 w0 = *(const float4*)(wp + ((size_t)k << 7));
        float4 w1 = *(const float4*)(wp + ((size_t)(k + 1) << 7));
        float s0[4], s1[4];
        #pragma unroll
        for (int r = 0; r < 4; ++r) {
            s0[r] = sS[((rowg << 2) + r) * 128 + k];
            s1[r] = sS[((rowg << 2) + r) * 128 + k + 1];
        }
        #pragma unroll
        for (int r = 0; r < 4; ++r) {
            acc2[r][0] = fmaf(s0[r], w0.x, acc2[r][0]);
            acc2[r][1] = fmaf(s0[r], w0.y, acc2[r][1]);
            acc2[r][2] = fmaf(s0[r], w0.z, acc2[r][2]);
            acc2[r][3] = fmaf(s0[r], w0.w, acc2[r][3]);
            acc2[r][0] = fmaf(s1[r], w1.x, acc2[r][0]);
            acc2[r][1] = fmaf(s1[r], w1.y, acc2[r][1]);
            acc2[r][2] = fmaf(s1[r], w1.z, acc2[r][2]);
            acc2[r][3] = fmaf(s1[r], w1.w, acc2[r][3]);
        }
    }
    float* outp = hn + (size_t)row0 * 128;
    #pragma unroll
    for (int r = 0; r < 4; ++r) {
        float4 o;
        o.x = fmaxf(acc2[r][0], 0.f);
        o.y = fmaxf(acc2[r][1], 0.f);
        o.z = fmaxf(acc2[r][2], 0.f);
        o.w = fmaxf(acc2[r][3], 0.f);
        *(float4*)(outp + ((rowg << 2) + r) * 128 + (colg << 2)) = o;
    }
}

// ---------------- fc_out: out = h@W_out + b_out ----------------
__global__ __launch_bounds__(256, 3) void fc_out_kernel(const float* __restrict__ h,
                                                        const float* __restrict__ W,
                                                        const float* __restrict__ b,
                                                        float* __restrict__ out, int n) {
    __shared__ float sW[128 * 40];    // 20KB
    __shared__ float sA[64 * 128];    // 32KB
    const int tid = threadIdx.x;
    #pragma unroll
    for (int t = 0; t < 5; ++t)
        ((float4*)sW)[t * 256 + tid] = ((const float4*)W)[t * 256 + tid];
    const int row0 = blockIdx.x * 64;
    #pragma unroll
    for (int t = 0; t < 8; ++t) {
        int idx = t * 256 + tid;              // float4 index, 2048 total
        int row = idx >> 5;
        int gr = row0 + row;
        float4 v = make_float4(0.f, 0.f, 0.f, 0.f);
        if (gr < n) v = ((const float4*)h)[(size_t)gr * 32 + (idx & 31)];
        ((float4*)sA)[idx] = v;
    }
    __syncthreads();

    const int rowg = tid >> 3;   // 32 groups x 2 rows
    const int colg = tid & 7;    // 8 groups x 5 cols
    float acc[2][5];
    #pragma unroll
    for (int c = 0; c < 5; ++c) {
        float bb = b[colg * 5 + c];
        acc[0][c] = bb; acc[1][c] = bb;
    }
    for (int k = 0; k < 128; ++k) {
        float s0 = sA[(rowg * 2 + 0) * 128 + k];
        float s1 = sA[(rowg * 2 + 1) * 128 + k];
        #pragma unroll
        for (int c = 0; c < 5; ++c) {
            float w = sW[k * 40 + colg * 5 + c];
            acc[0][c] = fmaf(s0, w, acc[0][c]);
            acc[1][c] = fmaf(s1, w, acc[1][c]);
        }
    }
    #pragma unroll
    for (int rr = 0; rr < 2; ++rr) {
        int r = row0 + rowg * 2 + rr;
        if (r < n) {
            #pragma unroll
            for (int c = 0; c < 5; ++c)
                out[(size_t)r * 40 + colg * 5 + c] = acc[rr][c];
        }
    }
}

extern "C" void kernel_launch(void* const* d_in, const int* in_sizes, int n_in,
                              void* d_out, int out_size, void* d_ws, size_t ws_size,
                              hipStream_t stream) {
    const float* x      = (const float*)d_in[0];
    const int*   esrc   = (const int*)d_in[1];
    const int*   edst   = (const int*)d_in[2];
    const float* eval   = (const float*)d_in[3];
    const float* W_in   = (const float*)d_in[4];
    const float* b_in   = (const float*)d_in[5];
    const float* conv_w = (const float*)d_in[6];
    const float* W_out  = (const float*)d_in[7];
    const float* b_out  = (const float*)d_in[8];
    float* out = (float*)d_out;

    // workspace carve-up (~181 MB total)
    float* h0      = (float*)d_ws;
    float* hA      = h0 + (size_t)NN * 128;
    float* hB      = hA + (size_t)NN * 128;
    float* Wc      = hB + (size_t)NN * 128;
    int*   row_ptr = (int*)(Wc + 8 * 128 * 128);
    int*   cursor  = row_ptr + (NN + 2);      // padded for 8B alignment of csr
    int*   cnt     = cursor + NN;
    int2*  csr     = (int2*)(cnt + NN);

    // --- CSR build ---
    hipMemsetAsync(cnt, 0, NN * sizeof(int), stream);
    hist_kernel<<<EE / 256, 256, 0, stream>>>(edst, cnt, EE);
    scan_kernel<<<1, 1024, 0, stream>>>(cnt, row_ptr, cursor, NN);
    scatter_kernel<<<EE / 256, 256, 0, stream>>>(esrc, edst, eval, cursor, csr, EE);

    // --- weights prep ---
    prep_wc_kernel<<<dim3(64, 8), 256, 0, stream>>>(conv_w, Wc);

    // --- fc_in ---
    fc_in_kernel<<<NN / 32, 256, 0, stream>>>(x, W_in, b_in, h0);

    // --- 8 fused layers, ping-pong hA/hB ---
    const float* hin = h0;
    float* hout = hA;
    for (int i = 0; i < 8; ++i) {
        layer_kernel<<<NN / 32, 256, 0, stream>>>(hin, h0, csr, row_ptr, Wc + i * 16384, hout);
        hin = hout;
        hout = (hout == hA) ? hB : hA;
    }

    // --- fc_out ---
    fc_out_kernel<<<(NN + 63) / 64, 256, 0, stream>>>(hin, W_out, b_out, out, NN);
}

// Round 7
// 1892.824 us; speedup vs baseline: 1.3800x; 1.3800x over previous
//
#include <hip/hip_runtime.h>
#include <hip/hip_fp16.h>

// GCNII on MI355X. fp32 compute, fp16 storage for the gathered state.
//   1. CSR build by dst (hist -> scan -> scatter), once per call
//   2. Wc[i] = theta_i*conv_w[i] + (1-theta_i)*I   (absorbs identity-mapping mix)
//   3. h0 = x@W_in + b_in  (stored fp16)
//   4. 8x fused layer: wave-per-row CSR gather (8-deep, half2/lane, fp32 accum)
//      -> support -> LDS(fp32) -> @Wc (global fp32, L2-hot) -> relu -> store fp16
//   5. out = h@W_out + b_out  (h fp16 -> fp32 out)
// R3 change: h/h0/hn in fp16 -> halves the bandwidth-bound gather traffic.
// R4/R5/R6: resubmits (MI355X container unresponsive before benching).

constexpr int NN = 100000;
constexpr int EE = 3200000;

struct alignas(8) Half4 { __half2 lo, hi; };

// ---------------- CSR build ----------------
__global__ void hist_kernel(const int* __restrict__ dst, int* __restrict__ cnt, int e) {
    int i = blockIdx.x * 256 + threadIdx.x;
    if (i < e) atomicAdd(&cnt[dst[i]], 1);
}

__global__ __launch_bounds__(1024) void scan_kernel(const int* __restrict__ cnt,
                                                    int* __restrict__ row_ptr,
                                                    int* __restrict__ cursor, int n) {
    __shared__ int wsum[16];
    __shared__ int s_carry;
    const int lane = threadIdx.x & 63, wid = threadIdx.x >> 6;
    if (threadIdx.x == 0) s_carry = 0;
    __syncthreads();
    for (int base = 0; base < n; base += 1024) {
        int i = base + threadIdx.x;
        int v = (i < n) ? cnt[i] : 0;
        int x = v;
        #pragma unroll
        for (int d = 1; d < 64; d <<= 1) {
            int y = __shfl_up(x, (unsigned)d);
            if (lane >= d) x += y;
        }
        if (lane == 63) wsum[wid] = x;
        __syncthreads();
        int woff = 0;
        for (int w = 0; w < wid; ++w) woff += wsum[w];
        int carry = s_carry;
        if (i < n) {
            int excl = carry + woff + x - v;
            row_ptr[i] = excl;
            cursor[i] = excl;
        }
        __syncthreads();
        if (threadIdx.x == 1023) s_carry = carry + woff + x;
        __syncthreads();
    }
    if (threadIdx.x == 0) row_ptr[n] = s_carry;
}

__global__ void scatter_kernel(const int* __restrict__ src, const int* __restrict__ dst,
                               const float* __restrict__ val, int* __restrict__ cursor,
                               int2* __restrict__ csr, int e) {
    int i = blockIdx.x * 256 + threadIdx.x;
    if (i < e) {
        int p = atomicAdd(&cursor[dst[i]], 1);
        csr[p] = make_int2(src[i], __float_as_int(val[i]));
    }
}

// ---------------- Wc = theta*W + (1-theta)*I ----------------
__global__ void prep_wc_kernel(const float* __restrict__ conv_w, float* __restrict__ Wc) {
    int layer = blockIdx.y;
    int idx = blockIdx.x * 256 + threadIdx.x;          // 0..16383
    float theta = logf(0.5f / (float)(layer + 1) + 1.0f);
    int k = idx >> 7, j = idx & 127;
    float w = conv_w[layer * 16384 + idx];
    Wc[layer * 16384 + idx] = theta * w + ((k == j) ? (1.0f - theta) : 0.0f);
}

// ---------------- fc_in: h0 = x@W_in + b_in (fp16 out) ----------------
__global__ __launch_bounds__(256, 2) void fc_in_kernel(const float* __restrict__ x,
                                                       const float* __restrict__ W,
                                                       const float* __restrict__ b,
                                                       __half* __restrict__ h0) {
    __shared__ float sW[128 * 128];   // 64KB
    __shared__ float sA[32 * 128];    // 16KB
    const int tid = threadIdx.x;
    #pragma unroll
    for (int t = 0; t < 16; ++t)
        ((float4*)sW)[t * 256 + tid] = ((const float4*)W)[t * 256 + tid];
    const float4* xs = (const float4*)(x + (size_t)blockIdx.x * 32 * 128);
    #pragma unroll
    for (int t = 0; t < 4; ++t)
        ((float4*)sA)[t * 256 + tid] = xs[t * 256 + tid];
    __syncthreads();

    const int rowg = tid >> 5, colg = tid & 31;
    float4 bias = ((const float4*)b)[colg];
    float acc[4][4];
    #pragma unroll
    for (int r = 0; r < 4; ++r) { acc[r][0] = bias.x; acc[r][1] = bias.y; acc[r][2] = bias.z; acc[r][3] = bias.w; }

    for (int k = 0; k < 128; ++k) {
        float4 w = *(const float4*)&sW[k * 128 + (colg << 2)];
        float s[4];
        #pragma unroll
        for (int r = 0; r < 4; ++r) s[r] = sA[((rowg << 2) + r) * 128 + k];
        #pragma unroll
        for (int r = 0; r < 4; ++r) {
            acc[r][0] = fmaf(s[r], w.x, acc[r][0]);
            acc[r][1] = fmaf(s[r], w.y, acc[r][1]);
            acc[r][2] = fmaf(s[r], w.z, acc[r][2]);
            acc[r][3] = fmaf(s[r], w.w, acc[r][3]);
        }
    }
    const int row0 = blockIdx.x * 32;
    #pragma unroll
    for (int r = 0; r < 4; ++r) {
        Half4 o;
        o.lo = __floats2half2_rn(acc[r][0], acc[r][1]);
        o.hi = __floats2half2_rn(acc[r][2], acc[r][3]);
        *(Half4*)(h0 + ((size_t)(row0 + (rowg << 2) + r) << 7) + (colg << 2)) = o;
    }
}

// ---------------- fused layer ----------------
// Phase A: one wave per row (64 lanes x half2 = 256B). Row base wave-uniform.
//          8 gathers in flight, fp32 accumulation.
// Phase B: S (LDS fp32, 16KB) @ Wc (global fp32, L2-hot) -> relu -> fp16 store.
__global__ __launch_bounds__(256, 8) void layer_kernel(const __half* __restrict__ h,
                                                       const __half* __restrict__ h0,
                                                       const int2* __restrict__ csr,
                                                       const int* __restrict__ row_ptr,
                                                       const float* __restrict__ Wc,
                                                       __half* __restrict__ hn) {
    __shared__ float sS[32 * 128];    // 16KB
    const int tid = threadIdx.x;
    const int wid = tid >> 6, lane = tid & 63;
    const int fo = lane << 1;               // half-pair feature offset
    const int row0 = blockIdx.x * 32;
    const int rb = __builtin_amdgcn_readfirstlane(row0 + wid * 8);

    for (int rr = 0; rr < 8; ++rr) {
        const int r = rb + rr;
        const int e0 = row_ptr[r], e1 = row_ptr[r + 1];
        float2 acc0 = make_float2(0.f, 0.f), acc1 = make_float2(0.f, 0.f);
        int e = e0;
        for (; e + 8 <= e1; e += 8) {
            int2 p0 = csr[e + 0], p1 = csr[e + 1], p2 = csr[e + 2], p3 = csr[e + 3];
            int2 p4 = csr[e + 4], p5 = csr[e + 5], p6 = csr[e + 6], p7 = csr[e + 7];
            __half2 q0 = *(const __half2*)(h + ((size_t)p0.x << 7) + fo);
            __half2 q1 = *(const __half2*)(h + ((size_t)p1.x << 7) + fo);
            __half2 q2 = *(const __half2*)(h + ((size_t)p2.x << 7) + fo);
            __half2 q3 = *(const __half2*)(h + ((size_t)p3.x << 7) + fo);
            __half2 q4 = *(const __half2*)(h + ((size_t)p4.x << 7) + fo);
            __half2 q5 = *(const __half2*)(h + ((size_t)p5.x << 7) + fo);
            __half2 q6 = *(const __half2*)(h + ((size_t)p6.x << 7) + fo);
            __half2 q7 = *(const __half2*)(h + ((size_t)p7.x << 7) + fo);
            float2 g0 = __half22float2(q0), g1 = __half22float2(q1);
            float2 g2 = __half22float2(q2), g3 = __half22float2(q3);
            float2 g4 = __half22float2(q4), g5 = __half22float2(q5);
            float2 g6 = __half22float2(q6), g7 = __half22float2(q7);
            float v0 = __int_as_float(p0.y), v1 = __int_as_float(p1.y);
            float v2 = __int_as_float(p2.y), v3 = __int_as_float(p3.y);
            float v4 = __int_as_float(p4.y), v5 = __int_as_float(p5.y);
            float v6 = __int_as_float(p6.y), v7 = __int_as_float(p7.y);
            acc0.x = fmaf(v0, g0.x, acc0.x); acc0.y = fmaf(v0, g0.y, acc0.y);
            acc1.x = fmaf(v1, g1.x, acc1.x); acc1.y = fmaf(v1, g1.y, acc1.y);
            acc0.x = fmaf(v2, g2.x, acc0.x); acc0.y = fmaf(v2, g2.y, acc0.y);
            acc1.x = fmaf(v3, g3.x, acc1.x); acc1.y = fmaf(v3, g3.y, acc1.y);
            acc0.x = fmaf(v4, g4.x, acc0.x); acc0.y = fmaf(v4, g4.y, acc0.y);
            acc1.x = fmaf(v5, g5.x, acc1.x); acc1.y = fmaf(v5, g5.y, acc1.y);
            acc0.x = fmaf(v6, g6.x, acc0.x); acc0.y = fmaf(v6, g6.y, acc0.y);
            acc1.x = fmaf(v7, g7.x, acc1.x); acc1.y = fmaf(v7, g7.y, acc1.y);
        }
        if (e < e1) {                         // one masked 8-wide tail iteration
            int2 pk[8];
            #pragma unroll
            for (int k = 0; k < 8; ++k)
                pk[k] = csr[(e + k < e1) ? (e + k) : (e1 - 1)];
            #pragma unroll
            for (int k = 0; k < 8; ++k) {
                float v = (e + k < e1) ? __int_as_float(pk[k].y) : 0.f;
                float2 g = __half22float2(*(const __half2*)(h + ((size_t)pk[k].x << 7) + fo));
                if (k & 1) { acc1.x = fmaf(v, g.x, acc1.x); acc1.y = fmaf(v, g.y, acc1.y); }
                else       { acc0.x = fmaf(v, g.x, acc0.x); acc0.y = fmaf(v, g.y, acc0.y); }
            }
        }
        float2 h0v = __half22float2(*(const __half2*)(h0 + ((size_t)r << 7) + fo));
        float2 sv;
        sv.x = 0.9f * (acc0.x + acc1.x) + 0.1f * h0v.x;
        sv.y = 0.9f * (acc0.y + acc1.y) + 0.1f * h0v.y;
        *(float2*)&sS[(wid * 8 + rr) * 128 + fo] = sv;
    }
    __syncthreads();

    // Phase B: out = S @ Wc, relu, fp16 store. Wc from global (64KB, L1/L2-hot).
    const int rowg = tid >> 5, colg = tid & 31;
    const float* wp = Wc + (colg << 2);
    float acc2[4][4] = {};
    for (int k = 0; k < 128; k += 2) {
        float4 w0 = *(const float4*)(wp + ((size_t)k << 7));
        float4 w1 = *(const float4*)(wp + ((size_t)(k + 1) << 7));
        float s0[4], s1[4];
        #pragma unroll
        for (int r = 0; r < 4; ++r) {
            s0[r] = sS[((rowg << 2) + r) * 128 + k];
            s1[r] = sS[((rowg << 2) + r) * 128 + k + 1];
        }
        #pragma unroll
        for (int r = 0; r < 4; ++r) {
            acc2[r][0] = fmaf(s0[r], w0.x, acc2[r][0]);
            acc2[r][1] = fmaf(s0[r], w0.y, acc2[r][1]);
            acc2[r][2] = fmaf(s0[r], w0.z, acc2[r][2]);
            acc2[r][3] = fmaf(s0[r], w0.w, acc2[r][3]);
            acc2[r][0] = fmaf(s1[r], w1.x, acc2[r][0]);
            acc2[r][1] = fmaf(s1[r], w1.y, acc2[r][1]);
            acc2[r][2] = fmaf(s1[r], w1.z, acc2[r][2]);
            acc2[r][3] = fmaf(s1[r], w1.w, acc2[r][3]);
        }
    }
    #pragma unroll
    for (int r = 0; r < 4; ++r) {
        Half4 o;
        o.lo = __floats2half2_rn(fmaxf(acc2[r][0], 0.f), fmaxf(acc2[r][1], 0.f));
        o.hi = __floats2half2_rn(fmaxf(acc2[r][2], 0.f), fmaxf(acc2[r][3], 0.f));
        *(Half4*)(hn + ((size_t)(row0 + (rowg << 2) + r) << 7) + (colg << 2)) = o;
    }
}

// ---------------- fc_out: out = h(fp16)@W_out + b_out ----------------
__global__ __launch_bounds__(256, 3) void fc_out_kernel(const __half* __restrict__ h,
                                                        const float* __restrict__ W,
                                                        const float* __restrict__ b,
                                                        float* __restrict__ out, int n) {
    __shared__ float sW[128 * 40];    // 20KB
    __shared__ float sA[64 * 128];    // 32KB
    const int tid = threadIdx.x;
    #pragma unroll
    for (int t = 0; t < 5; ++t)
        ((float4*)sW)[t * 256 + tid] = ((const float4*)W)[t * 256 + tid];
    const int row0 = blockIdx.x * 64;
    #pragma unroll
    for (int t = 0; t < 8; ++t) {
        int idx = t * 256 + tid;              // 4-half chunk index, 2048 total
        int row = idx >> 5;                   // 32 chunks per 128-feat row
        int gr = row0 + row;
        float4 v = make_float4(0.f, 0.f, 0.f, 0.f);
        if (gr < n) {
            Half4 q = *(const Half4*)(h + ((size_t)gr << 7) + ((idx & 31) << 2));
            float2 a = __half22float2(q.lo), c = __half22float2(q.hi);
            v = make_float4(a.x, a.y, c.x, c.y);
        }
        *(float4*)&sA[row * 128 + ((idx & 31) << 2)] = v;
    }
    __syncthreads();

    const int rowg = tid >> 3;   // 32 groups x 2 rows
    const int colg = tid & 7;    // 8 groups x 5 cols
    float acc[2][5];
    #pragma unroll
    for (int c = 0; c < 5; ++c) {
        float bb = b[colg * 5 + c];
        acc[0][c] = bb; acc[1][c] = bb;
    }
    for (int k = 0; k < 128; ++k) {
        float s0 = sA[(rowg * 2 + 0) * 128 + k];
        float s1 = sA[(rowg * 2 + 1) * 128 + k];
        #pragma unroll
        for (int c = 0; c < 5; ++c) {
            float w = sW[k * 40 + colg * 5 + c];
            acc[0][c] = fmaf(s0, w, acc[0][c]);
            acc[1][c] = fmaf(s1, w, acc[1][c]);
        }
    }
    #pragma unroll
    for (int rr = 0; rr < 2; ++rr) {
        int r = row0 + rowg * 2 + rr;
        if (r < n) {
            #pragma unroll
            for (int c = 0; c < 5; ++c)
                out[(size_t)r * 40 + colg * 5 + c] = acc[rr][c];
        }
    }
}

extern "C" void kernel_launch(void* const* d_in, const int* in_sizes, int n_in,
                              void* d_out, int out_size, void* d_ws, size_t ws_size,
                              hipStream_t stream) {
    const float* x      = (const float*)d_in[0];
    const int*   esrc   = (const int*)d_in[1];
    const int*   edst   = (const int*)d_in[2];
    const float* eval   = (const float*)d_in[3];
    const float* W_in   = (const float*)d_in[4];
    const float* b_in   = (const float*)d_in[5];
    const float* conv_w = (const float*)d_in[6];
    const float* W_out  = (const float*)d_in[7];
    const float* b_out  = (const float*)d_in[8];
    float* out = (float*)d_out;

    // workspace carve-up (~103 MB total)
    __half* h0     = (__half*)d_ws;
    __half* hA     = h0 + (size_t)NN * 128;
    __half* hB     = hA + (size_t)NN * 128;
    float*  Wc     = (float*)(hB + (size_t)NN * 128);
    int*   row_ptr = (int*)(Wc + 8 * 128 * 128);
    int*   cursor  = row_ptr + (NN + 2);      // padded so csr stays 8B-aligned
    int*   cnt     = cursor + NN;
    int2*  csr     = (int2*)(cnt + NN);

    // --- CSR build ---
    hipMemsetAsync(cnt, 0, NN * sizeof(int), stream);
    hist_kernel<<<EE / 256, 256, 0, stream>>>(edst, cnt, EE);
    scan_kernel<<<1, 1024, 0, stream>>>(cnt, row_ptr, cursor, NN);
    scatter_kernel<<<EE / 256, 256, 0, stream>>>(esrc, edst, eval, cursor, csr, EE);

    // --- weights prep ---
    prep_wc_kernel<<<dim3(64, 8), 256, 0, stream>>>(conv_w, Wc);

    // --- fc_in ---
    fc_in_kernel<<<NN / 32, 256, 0, stream>>>(x, W_in, b_in, h0);

    // --- 8 fused layers, ping-pong hA/hB ---
    const __half* hin = h0;
    __half* hout = hA;
    for (int i = 0; i < 8; ++i) {
        layer_kernel<<<NN / 32, 256, 0, stream>>>(hin, h0, csr, row_ptr, Wc + i * 16384, hout);
        hin = hout;
        hout = (hout == hA) ? hB : hA;
    }

    // --- fc_out ---
    fc_out_kernel<<<(NN + 63) / 64, 256, 0, stream>>>(hin, W_out, b_out, out, NN);
}

// Round 8
// 1522.062 us; speedup vs baseline: 1.7162x; 1.2436x over previous
//
#include <hip/hip_runtime.h>
#include <hip/hip_fp16.h>

// GCNII on MI355X. fp32 compute, fp16 storage for the gathered state.
//   CSR build (R7 redesign, bucket-local for write locality):
//     k1 bhist:    LDS-aggregated 256-bucket histogram (dst>>9)
//     k2 bscan:    scan 256 buckets -> bbase/bcur; row_ptr[N]=E
//     k3 bucket:   LDS counting-sort 4096-edge chunks -> bucket-ordered bsorted/bdst
//     k4 finalize: per-bucket (512 nodes) LDS hist+scan -> row_ptr, LDS-cursor
//                  scatter -> csr (writes confined to L2-resident bucket range)
//   Wc[i] = theta_i*conv_w[i] + (1-theta_i)*I  (absorbs identity-mapping mix)
//   h0 = x@W_in + b_in (fp16)
//   8x fused layer: wave-per-row CSR gather (2 edges/instr: half-wave x Half4,
//     16 edges in flight, fp32 accum) -> support -> LDS -> @Wc -> relu -> fp16
//   out = h@W_out + b_out

constexpr int NN = 100000;
constexpr int EE = 3200000;
constexpr int NB = 256;          // buckets, dst>>9 (512 nodes each)
constexpr int NBUCK = (NN + 511) / 512;   // 196 used buckets

struct alignas(8) Half4 { __half2 lo, hi; };

// ---------------- k1: bucket histogram (LDS-aggregated) ----------------
__global__ __launch_bounds__(256) void bhist_kernel(const int* __restrict__ dst,
                                                    int* __restrict__ bhist, int e) {
    __shared__ int lh[NB];
    lh[threadIdx.x] = 0;
    __syncthreads();
    for (int i = blockIdx.x * 256 + threadIdx.x; i < e; i += gridDim.x * 256)
        atomicAdd(&lh[dst[i] >> 9], 1);
    __syncthreads();
    if (lh[threadIdx.x]) atomicAdd(&bhist[threadIdx.x], lh[threadIdx.x]);
}

// ---------------- k2: bucket scan ----------------
__global__ void bscan_kernel(const int* __restrict__ bhist, int* __restrict__ bbase,
                             int* __restrict__ bcur, int* __restrict__ row_ptr) {
    if (threadIdx.x == 0) {
        int s = 0;
        for (int b = 0; b < NB; ++b) { bbase[b] = s; bcur[b] = s; s += bhist[b]; }
        bbase[NB] = s;
        row_ptr[NN] = s;
    }
}

// ---------------- k3: chunk counting-sort into buckets ----------------
__global__ __launch_bounds__(256, 3) void bucket_kernel(const int* __restrict__ src,
                                                        const int* __restrict__ dst,
                                                        const float* __restrict__ val,
                                                        int* __restrict__ bcur,
                                                        int2* __restrict__ bsorted,
                                                        int* __restrict__ bdst, int e_total) {
    __shared__ int bin_cnt[NB], bin_excl[NB], bin_gbase[NB], bin_cur[NB];
    __shared__ int2 s_ed[4096];   // 32KB
    __shared__ int  s_dp[4096];   // 16KB
    const int tid = threadIdx.x;
    const int e_base = blockIdx.x * 4096;
    const int count = min(4096, e_total - e_base);
    bin_cnt[tid] = 0;
    __syncthreads();
    #pragma unroll
    for (int i = 0; i < 16; ++i) {
        int idx = e_base + i * 256 + tid;
        if (idx < e_total) atomicAdd(&bin_cnt[dst[idx] >> 9], 1);
    }
    __syncthreads();
    if (tid == 0) {
        int s = 0;
        for (int b = 0; b < NB; ++b) { bin_excl[b] = s; s += bin_cnt[b]; }
    }
    __syncthreads();
    bin_gbase[tid] = atomicAdd(&bcur[tid], bin_cnt[tid]);
    bin_cur[tid] = bin_excl[tid];
    __syncthreads();
    #pragma unroll
    for (int i = 0; i < 16; ++i) {
        int idx = e_base + i * 256 + tid;
        if (idx < e_total) {
            int d = dst[idx];
            int pos = atomicAdd(&bin_cur[d >> 9], 1);
            s_ed[pos] = make_int2(src[idx], __float_as_int(val[idx]));
            s_dp[pos] = d;
        }
    }
    __syncthreads();
    for (int pos = tid; pos < count; pos += 256) {
        int d = s_dp[pos], b = d >> 9;
        int g = bin_gbase[b] + (pos - bin_excl[b]);
        bsorted[g] = s_ed[pos];
        bdst[g] = d;
    }
}

// ---------------- k4: per-bucket finalize (row_ptr + csr) ----------------
__global__ __launch_bounds__(512) void finalize_kernel(const int2* __restrict__ bsorted,
                                                       const int* __restrict__ bdst,
                                                       const int* __restrict__ bbase,
                                                       int* __restrict__ row_ptr,
                                                       int2* __restrict__ csr) {
    __shared__ int hist[512], cur[512], wsum[8];
    const int tid = threadIdx.x, lane = tid & 63, wid = tid >> 6;
    const int b = blockIdx.x;
    const int n0 = b << 9;
    const int nodes = min(512, NN - n0);
    const int es = bbase[b], ee = bbase[b + 1], cnt = ee - es;
    hist[tid] = 0;
    __syncthreads();
    for (int i = tid; i < cnt; i += 512) atomicAdd(&hist[bdst[es + i] - n0], 1);
    __syncthreads();
    int v = hist[tid];
    int x = v;
    #pragma unroll
    for (int d = 1; d < 64; d <<= 1) {
        int y = __shfl_up(x, (unsigned)d);
        if (lane >= d) x += y;
    }
    if (lane == 63) wsum[wid] = x;
    __syncthreads();
    if (tid == 0) {
        int s = 0;
        for (int w = 0; w < 8; ++w) { int t2 = wsum[w]; wsum[w] = s; s += t2; }
    }
    __syncthreads();
    int excl = x - v + wsum[wid];
    cur[tid] = excl;
    if (tid < nodes) row_ptr[n0 + tid] = es + excl;
    __syncthreads();
    for (int i = tid; i < cnt; i += 512) {
        int d = bdst[es + i];
        int p = atomicAdd(&cur[d - n0], 1);
        csr[es + p] = bsorted[es + i];
    }
}

// ---------------- Wc = theta*W + (1-theta)*I ----------------
__global__ void prep_wc_kernel(const float* __restrict__ conv_w, float* __restrict__ Wc) {
    int layer = blockIdx.y;
    int idx = blockIdx.x * 256 + threadIdx.x;          // 0..16383
    float theta = logf(0.5f / (float)(layer + 1) + 1.0f);
    int k = idx >> 7, j = idx & 127;
    float w = conv_w[layer * 16384 + idx];
    Wc[layer * 16384 + idx] = theta * w + ((k == j) ? (1.0f - theta) : 0.0f);
}

// ---------------- fc_in: h0 = x@W_in + b_in (fp16 out) ----------------
__global__ __launch_bounds__(256, 2) void fc_in_kernel(const float* __restrict__ x,
                                                       const float* __restrict__ W,
                                                       const float* __restrict__ b,
                                                       __half* __restrict__ h0) {
    __shared__ float sW[128 * 128];   // 64KB
    __shared__ float sA[32 * 128];    // 16KB
    const int tid = threadIdx.x;
    #pragma unroll
    for (int t = 0; t < 16; ++t)
        ((float4*)sW)[t * 256 + tid] = ((const float4*)W)[t * 256 + tid];
    const float4* xs = (const float4*)(x + (size_t)blockIdx.x * 32 * 128);
    #pragma unroll
    for (int t = 0; t < 4; ++t)
        ((float4*)sA)[t * 256 + tid] = xs[t * 256 + tid];
    __syncthreads();

    const int rowg = tid >> 5, colg = tid & 31;
    float4 bias = ((const float4*)b)[colg];
    float acc[4][4];
    #pragma unroll
    for (int r = 0; r < 4; ++r) { acc[r][0] = bias.x; acc[r][1] = bias.y; acc[r][2] = bias.z; acc[r][3] = bias.w; }

    for (int k = 0; k < 128; ++k) {
        float4 w = *(const float4*)&sW[k * 128 + (colg << 2)];
        float s[4];
        #pragma unroll
        for (int r = 0; r < 4; ++r) s[r] = sA[((rowg << 2) + r) * 128 + k];
        #pragma unroll
        for (int r = 0; r < 4; ++r) {
            acc[r][0] = fmaf(s[r], w.x, acc[r][0]);
            acc[r][1] = fmaf(s[r], w.y, acc[r][1]);
            acc[r][2] = fmaf(s[r], w.z, acc[r][2]);
            acc[r][3] = fmaf(s[r], w.w, acc[r][3]);
        }
    }
    const int row0 = blockIdx.x * 32;
    #pragma unroll
    for (int r = 0; r < 4; ++r) {
        Half4 o;
        o.lo = __floats2half2_rn(acc[r][0], acc[r][1]);
        o.hi = __floats2half2_rn(acc[r][2], acc[r][3]);
        *(Half4*)(h0 + ((size_t)(row0 + (rowg << 2) + r) << 7) + (colg << 2)) = o;
    }
}

#define FMA4(ACC, PV, G) { \
    float vv_ = __int_as_float((PV).y); \
    float2 lo_ = __half22float2((G).lo), hi_ = __half22float2((G).hi); \
    (ACC).x = fmaf(vv_, lo_.x, (ACC).x); (ACC).y = fmaf(vv_, lo_.y, (ACC).y); \
    (ACC).z = fmaf(vv_, hi_.x, (ACC).z); (ACC).w = fmaf(vv_, hi_.y, (ACC).w); }

// ---------------- fused layer ----------------
// Phase A: one wave per row; 2 edges per VMEM instr (half-wave each, Half4/lane,
//          32 lanes = 256B row), 16 edges in flight, fp32 accum, shfl-combine.
// Phase B: S (LDS fp32, 16KB) @ Wc (global fp32, L2-hot) -> relu -> fp16 store.
__global__ __launch_bounds__(256, 8) void layer_kernel(const __half* __restrict__ h,
                                                       const __half* __restrict__ h0,
                                                       const int2* __restrict__ csr,
                                                       const int* __restrict__ row_ptr,
                                                       const float* __restrict__ Wc,
                                                       __half* __restrict__ hn) {
    __shared__ float sS[32 * 128];    // 16KB
    const int tid = threadIdx.x;
    const int wid = tid >> 6, lane = tid & 63;
    const int sub = lane >> 5;              // which edge of the pair
    const int q4 = (lane & 31) << 2;        // half offset within the 128-wide row
    const int row0 = blockIdx.x * 32;
    const int rb = __builtin_amdgcn_readfirstlane(row0 + wid * 8);

    for (int rr = 0; rr < 8; ++rr) {
        const int r = rb + rr;
        const int e0 = row_ptr[r], e1 = row_ptr[r + 1];
        float4 accA = make_float4(0.f, 0.f, 0.f, 0.f);
        float4 accB = make_float4(0.f, 0.f, 0.f, 0.f);
        int e = e0;
        for (; e + 16 <= e1; e += 16) {
            int2 c0 = csr[e + 0],  c1 = csr[e + 1],  c2 = csr[e + 2],  c3 = csr[e + 3];
            int2 c4 = csr[e + 4],  c5 = csr[e + 5],  c6 = csr[e + 6],  c7 = csr[e + 7];
            int2 c8 = csr[e + 8],  c9 = csr[e + 9],  c10 = csr[e + 10], c11 = csr[e + 11];
            int2 c12 = csr[e + 12], c13 = csr[e + 13], c14 = csr[e + 14], c15 = csr[e + 15];
            int2 p0 = sub ? c1 : c0;
            int2 p1 = sub ? c3 : c2;
            int2 p2 = sub ? c5 : c4;
            int2 p3 = sub ? c7 : c6;
            int2 p4 = sub ? c9 : c8;
            int2 p5 = sub ? c11 : c10;
            int2 p6 = sub ? c13 : c12;
            int2 p7 = sub ? c15 : c14;
            Half4 g0 = *(const Half4*)(h + ((size_t)p0.x << 7) + q4);
            Half4 g1 = *(const Half4*)(h + ((size_t)p1.x << 7) + q4);
            Half4 g2 = *(const Half4*)(h + ((size_t)p2.x << 7) + q4);
            Half4 g3 = *(const Half4*)(h + ((size_t)p3.x << 7) + q4);
            Half4 g4 = *(const Half4*)(h + ((size_t)p4.x << 7) + q4);
            Half4 g5 = *(const Half4*)(h + ((size_t)p5.x << 7) + q4);
            Half4 g6 = *(const Half4*)(h + ((size_t)p6.x << 7) + q4);
            Half4 g7 = *(const Half4*)(h + ((size_t)p7.x << 7) + q4);
            FMA4(accA, p0, g0); FMA4(accB, p1, g1);
            FMA4(accA, p2, g2); FMA4(accB, p3, g3);
            FMA4(accA, p4, g4); FMA4(accB, p5, g5);
            FMA4(accA, p6, g6); FMA4(accB, p7, g7);
        }
        if (e < e1) {                       // one masked 16-wide tail block
            #pragma unroll
            for (int k = 0; k < 8; ++k) {
                int iL = e + 2 * k;
                int2 cl = csr[(iL < e1) ? iL : (e1 - 1)];
                int2 ch = csr[(iL + 1 < e1) ? (iL + 1) : (e1 - 1)];
                int2 p = sub ? ch : cl;
                if (iL + sub >= e1) p.y = 0;       // zero the weight, keep clamped src
                Half4 g = *(const Half4*)(h + ((size_t)p.x << 7) + q4);
                if (k & 1) { FMA4(accB, p, g); } else { FMA4(accA, p, g); }
            }
        }
        float4 acc;
        acc.x = accA.x + accB.x; acc.y = accA.y + accB.y;
        acc.z = accA.z + accB.z; acc.w = accA.w + accB.w;
        acc.x += __shfl_xor(acc.x, 32);
        acc.y += __shfl_xor(acc.y, 32);
        acc.z += __shfl_xor(acc.z, 32);
        acc.w += __shfl_xor(acc.w, 32);
        if (sub == 0) {
            Half4 q = *(const Half4*)(h0 + ((size_t)r << 7) + q4);
            float2 a = __half22float2(q.lo), c = __half22float2(q.hi);
            float4 sv;
            sv.x = 0.9f * acc.x + 0.1f * a.x;
            sv.y = 0.9f * acc.y + 0.1f * a.y;
            sv.z = 0.9f * acc.z + 0.1f * c.x;
            sv.w = 0.9f * acc.w + 0.1f * c.y;
            *(float4*)&sS[(wid * 8 + rr) * 128 + q4] = sv;
        }
    }
    __syncthreads();

    // Phase B: out = S @ Wc, relu, fp16 store. Wc from global (64KB, L1/L2-hot).
    const int rowg = tid >> 5, colg = tid & 31;
    const float* wp = Wc + (colg << 2);
    float acc2[4][4] = {};
    for (int k = 0; k < 128; k += 2) {
        float4 w0 = *(const float4*)(wp + ((size_t)k << 7));
        float4 w1 = *(const float4*)(wp + ((size_t)(k + 1) << 7));
        float s0[4], s1[4];
        #pragma unroll
        for (int r = 0; r < 4; ++r) {
            s0[r] = sS[((rowg << 2) + r) * 128 + k];
            s1[r] = sS[((rowg << 2) + r) * 128 + k + 1];
        }
        #pragma unroll
        for (int r = 0; r < 4; ++r) {
            acc2[r][0] = fmaf(s0[r], w0.x, acc2[r][0]);
            acc2[r][1] = fmaf(s0[r], w0.y, acc2[r][1]);
            acc2[r][2] = fmaf(s0[r], w0.z, acc2[r][2]);
            acc2[r][3] = fmaf(s0[r], w0.w, acc2[r][3]);
            acc2[r][0] = fmaf(s1[r], w1.x, acc2[r][0]);
            acc2[r][1] = fmaf(s1[r], w1.y, acc2[r][1]);
            acc2[r][2] = fmaf(s1[r], w1.z, acc2[r][2]);
            acc2[r][3] = fmaf(s1[r], w1.w, acc2[r][3]);
        }
    }
    #pragma unroll
    for (int r = 0; r < 4; ++r) {
        Half4 o;
        o.lo = __floats2half2_rn(fmaxf(acc2[r][0], 0.f), fmaxf(acc2[r][1], 0.f));
        o.hi = __floats2half2_rn(fmaxf(acc2[r][2], 0.f), fmaxf(acc2[r][3], 0.f));
        *(Half4*)(hn + ((size_t)(row0 + (rowg << 2) + r) << 7) + (colg << 2)) = o;
    }
}

// ---------------- fc_out: out = h(fp16)@W_out + b_out ----------------
__global__ __launch_bounds__(256, 3) void fc_out_kernel(const __half* __restrict__ h,
                                                        const float* __restrict__ W,
                                                        const float* __restrict__ b,
                                                        float* __restrict__ out, int n) {
    __shared__ float sW[128 * 40];    // 20KB
    __shared__ float sA[64 * 128];    // 32KB
    const int tid = threadIdx.x;
    #pragma unroll
    for (int t = 0; t < 5; ++t)
        ((float4*)sW)[t * 256 + tid] = ((const float4*)W)[t * 256 + tid];
    const int row0 = blockIdx.x * 64;
    #pragma unroll
    for (int t = 0; t < 8; ++t) {
        int idx = t * 256 + tid;              // 4-half chunk index, 2048 total
        int row = idx >> 5;                   // 32 chunks per 128-feat row
        int gr = row0 + row;
        float4 v = make_float4(0.f, 0.f, 0.f, 0.f);
        if (gr < n) {
            Half4 q = *(const Half4*)(h + ((size_t)gr << 7) + ((idx & 31) << 2));
            float2 a = __half22float2(q.lo), c = __half22float2(q.hi);
            v = make_float4(a.x, a.y, c.x, c.y);
        }
        *(float4*)&sA[row * 128 + ((idx & 31) << 2)] = v;
    }
    __syncthreads();

    const int rowg = tid >> 3;   // 32 groups x 2 rows
    const int colg = tid & 7;    // 8 groups x 5 cols
    float acc[2][5];
    #pragma unroll
    for (int c = 0; c < 5; ++c) {
        float bb = b[colg * 5 + c];
        acc[0][c] = bb; acc[1][c] = bb;
    }
    for (int k = 0; k < 128; ++k) {
        float s0 = sA[(rowg * 2 + 0) * 128 + k];
        float s1 = sA[(rowg * 2 + 1) * 128 + k];
        #pragma unroll
        for (int c = 0; c < 5; ++c) {
            float w = sW[k * 40 + colg * 5 + c];
            acc[0][c] = fmaf(s0, w, acc[0][c]);
            acc[1][c] = fmaf(s1, w, acc[1][c]);
        }
    }
    #pragma unroll
    for (int rr = 0; rr < 2; ++rr) {
        int r = row0 + rowg * 2 + rr;
        if (r < n) {
            #pragma unroll
            for (int c = 0; c < 5; ++c)
                out[(size_t)r * 40 + colg * 5 + c] = acc[rr][c];
        }
    }
}

extern "C" void kernel_launch(void* const* d_in, const int* in_sizes, int n_in,
                              void* d_out, int out_size, void* d_ws, size_t ws_size,
                              hipStream_t stream) {
    const float* x      = (const float*)d_in[0];
    const int*   esrc   = (const int*)d_in[1];
    const int*   edst   = (const int*)d_in[2];
    const float* eval   = (const float*)d_in[3];
    const float* W_in   = (const float*)d_in[4];
    const float* b_in   = (const float*)d_in[5];
    const float* conv_w = (const float*)d_in[6];
    const float* W_out  = (const float*)d_in[7];
    const float* b_out  = (const float*)d_in[8];
    float* out = (float*)d_out;

    // workspace carve-up (~142 MB total)
    __half* h0     = (__half*)d_ws;
    __half* hA     = h0 + (size_t)NN * 128;
    __half* hB     = hA + (size_t)NN * 128;
    float*  Wc     = (float*)(hB + (size_t)NN * 128);
    int*   row_ptr = (int*)(Wc + 8 * 128 * 128);          // NN+2 ints
    int*   bhist   = row_ptr + (NN + 2);                  // 256
    int*   bbase   = bhist + NB;                          // 258 (NB+1, padded even)
    int*   bcur    = bbase + (NB + 2);                    // 256
    int2*  csr     = (int2*)(bcur + NB);                  // EE int2 (8B-aligned)
    int2*  bsorted = csr + EE;                            // EE int2
    int*   bdst    = (int*)(bsorted + EE);                // EE ints

    // --- CSR build (bucket-local) ---
    hipMemsetAsync(bhist, 0, NB * sizeof(int), stream);
    bhist_kernel<<<1024, 256, 0, stream>>>(edst, bhist, EE);
    bscan_kernel<<<1, 64, 0, stream>>>(bhist, bbase, bcur, row_ptr);
    bucket_kernel<<<(EE + 4095) / 4096, 256, 0, stream>>>(esrc, edst, eval, bcur,
                                                          bsorted, bdst, EE);
    finalize_kernel<<<NBUCK, 512, 0, stream>>>(bsorted, bdst, bbase, row_ptr, csr);

    // --- weights prep ---
    prep_wc_kernel<<<dim3(64, 8), 256, 0, stream>>>(conv_w, Wc);

    // --- fc_in ---
    fc_in_kernel<<<NN / 32, 256, 0, stream>>>(x, W_in, b_in, h0);

    // --- 8 fused layers, ping-pong hA/hB ---
    const __half* hin = h0;
    __half* hout = hA;
    for (int i = 0; i < 8; ++i) {
        layer_kernel<<<NN / 32, 256, 0, stream>>>(hin, h0, csr, row_ptr, Wc + i * 16384, hout);
        hin = hout;
        hout = (hout == hA) ? hB : hA;
    }

    // --- fc_out ---
    fc_out_kernel<<<(NN + 63) / 64, 256, 0, stream>>>(hin, W_out, b_out, out, NN);
}